// Round 11
// baseline (155.844 us; speedup 1.0000x reference)
//
#include <hip/hip_runtime.h>

#define NF 128

typedef __attribute__((ext_vector_type(8))) short short8;
typedef __attribute__((ext_vector_type(4))) float f32x4;

__device__ inline ushort f2bf(float f) {
    uint u = __float_as_uint(f);
    return (ushort)((u + 0x7FFFu + ((u >> 16) & 1u)) >> 16);  // RNE
}
__device__ inline float bf2f(ushort u) {
    return __uint_as_float(((uint)u) << 16);
}

// ---------------------------------------------------------------------------
// Fused prep: zero cnt + convert W1/W2 (transposed) and x to bf16.
__global__ __launch_bounds__(256) void prep_kernel(
    const float* __restrict__ x, const float* __restrict__ W1,
    const float* __restrict__ W2, int* __restrict__ cnt,
    ushort* __restrict__ xb, ushort* __restrict__ W1t, ushort* __restrict__ W2t,
    int n_nodes, int n8) {
    int gid = blockIdx.x * 256 + threadIdx.x;
    int gstride = gridDim.x * 256;
    for (int i = gid; i < n_nodes; i += gstride) cnt[i] = 0;
    for (int i = gid; i < 128 * 128; i += gstride) {
        int k = i >> 7, n = i & 127;
        W1t[n * NF + k] = f2bf(W1[i]);
    }
    for (int i = gid; i < 128 * 64; i += gstride) {
        int k = i >> 6, n = i & 63;
        W2t[n * NF + k] = f2bf(W2[i]);
    }
    const float4* in4 = reinterpret_cast<const float4*>(x);
    for (int i = gid; i < n8; i += gstride) {
        float4 v0 = in4[i * 2], v1 = in4[i * 2 + 1];
        short8 o;
        o[0] = (short)f2bf(v0.x); o[1] = (short)f2bf(v0.y);
        o[2] = (short)f2bf(v0.z); o[3] = (short)f2bf(v0.w);
        o[4] = (short)f2bf(v1.x); o[5] = (short)f2bf(v1.y);
        o[6] = (short)f2bf(v1.z); o[7] = (short)f2bf(v1.w);
        *reinterpret_cast<short8*>(&xb[i * 8]) = o;
    }
}

// ---------------------------------------------------------------------------
// cnt[dst[e]] += 1
__global__ void hist_kernel(const int* __restrict__ dst, int* __restrict__ cnt,
                            int n_edges) {
    int i = blockIdx.x * blockDim.x + threadIdx.x;
    if (i < n_edges) atomicAdd(&cnt[dst[i]], 1);
}

// ---------------------------------------------------------------------------
// Each block: off0 = sum(cnt[0 .. bid*256)) (cnt is READ-ONLY here), then
// block-local inclusive scan of its chunk.  rowptr[i+1] = off0+incl;
// cursor[i] = off0+excl.  rowptr[0] = 0.
__global__ __launch_bounds__(256) void scan_apply_kernel(
    const int* __restrict__ cnt, int* __restrict__ rowptr,
    int* __restrict__ cursor, int n) {
    __shared__ int s[256];
    __shared__ int off0_sh;
    int t = threadIdx.x;
    int lim = (int)blockIdx.x * 256;
    int sum = 0;
    for (int i = t; i < lim; i += 256) sum += cnt[i];
    s[t] = sum;
    __syncthreads();
    for (int off = 128; off > 0; off >>= 1) {
        if (t < off) s[t] += s[t + off];
        __syncthreads();
    }
    if (t == 0) off0_sh = s[0];
    __syncthreads();
    int off0 = off0_sh;
    __syncthreads();
    int i = lim + t;
    int v = (i < n) ? cnt[i] : 0;
    s[t] = v;
    __syncthreads();
    for (int off = 1; off < 256; off <<= 1) {
        int a = (t >= off) ? s[t - off] : 0;
        __syncthreads();
        s[t] += a;
        __syncthreads();
    }
    if (i < n) {
        rowptr[i + 1] = off0 + s[t];
        cursor[i] = off0 + s[t] - v;
    }
    if (blockIdx.x == 0 && t == 0) rowptr[0] = 0;
}

// ---------------------------------------------------------------------------
// edge_src[cursor[dst[e]]++] = src[e]
__global__ void fill_kernel(const int* __restrict__ src,
                            const int* __restrict__ dst,
                            int* __restrict__ cursor,
                            int* __restrict__ edge_src, int n_edges) {
    int i = blockIdx.x * blockDim.x + threadIdx.x;
    if (i < n_edges) {
        int slot = atomicAdd(&cursor[dst[i]], 1);
        edge_src[slot] = src[i];
    }
}

// ---------------------------------------------------------------------------
// hn[i] = bf16( (sum_nbrs hb[j] + hb[i]) / (deg+1) ).  128-dim bf16 in/out.
// 16 lanes/node, short8 (16B) per lane; fp32 accumulate; x4 unroll.
__global__ __launch_bounds__(256) void aggregate_kernel(
    const ushort* __restrict__ hb, const int* __restrict__ rowptr,
    const int* __restrict__ edge_src, ushort* __restrict__ hn, int n_nodes) {
    int t = threadIdx.x;
    int g = t & 15;
    int node = blockIdx.x * 16 + (t >> 4);
    if (node >= n_nodes) return;
    const short8* h8 = reinterpret_cast<const short8*>(hb);  // row = 16 x short8
    int e0 = rowptr[node], e1 = rowptr[node + 1];
    float a0[8], a1[8], a2[8], a3[8];
    {
        short8 sv = h8[(size_t)node * 16 + g];  // self term
#pragma unroll
        for (int i = 0; i < 8; i++) {
            a0[i] = bf2f((ushort)sv[i]);
            a1[i] = 0.f; a2[i] = 0.f; a3[i] = 0.f;
        }
    }
    for (int base = e0; base < e1; base += 16) {
        int m = min(16, e1 - base);
        int sg = (base + g < e1) ? edge_src[base + g] : 0;
        int j = 0;
        for (; j + 4 <= m; j += 4) {
            int s0 = __shfl(sg, j, 16);
            int s1 = __shfl(sg, j + 1, 16);
            int s2 = __shfl(sg, j + 2, 16);
            int s3 = __shfl(sg, j + 3, 16);
            short8 v0 = h8[(size_t)s0 * 16 + g];
            short8 v1 = h8[(size_t)s1 * 16 + g];
            short8 v2 = h8[(size_t)s2 * 16 + g];
            short8 v3 = h8[(size_t)s3 * 16 + g];
#pragma unroll
            for (int i = 0; i < 8; i++) {
                a0[i] += bf2f((ushort)v0[i]);
                a1[i] += bf2f((ushort)v1[i]);
                a2[i] += bf2f((ushort)v2[i]);
                a3[i] += bf2f((ushort)v3[i]);
            }
        }
        for (; j < m; ++j) {
            int s = __shfl(sg, j, 16);
            short8 v = h8[(size_t)s * 16 + g];
#pragma unroll
            for (int i = 0; i < 8; i++) a0[i] += bf2f((ushort)v[i]);
        }
    }
    float inv = 1.0f / (float)(e1 - e0 + 1);
    short8 o;
#pragma unroll
    for (int i = 0; i < 8; i++)
        o[i] = (short)f2bf((a0[i] + a1[i] + a2[i] + a3[i]) * inv);
    reinterpret_cast<short8*>(hn)[(size_t)node * 16 + g] = o;
}

// ---------------------------------------------------------------------------
// out[i] = (sum_nbrs y[j] + y[i]) / (deg+1) + b.   64-dim bf16 in, fp32 out.
// 8 lanes/node, short8 (16B) per lane; 32 nodes/block.
__global__ __launch_bounds__(256) void aggregate64_kernel(
    const ushort* __restrict__ y, const int* __restrict__ rowptr,
    const int* __restrict__ edge_src, const float* __restrict__ b,
    float* __restrict__ out, int n_nodes) {
    int t = threadIdx.x;
    int g = t & 7;
    int node = blockIdx.x * 32 + (t >> 3);
    if (node >= n_nodes) return;
    const short8* y8 = reinterpret_cast<const short8*>(y);  // row = 8 x short8
    int e0 = rowptr[node], e1 = rowptr[node + 1];
    float a0[8], a1[8], a2[8], a3[8];
    {
        short8 sv = y8[(size_t)node * 8 + g];  // self term
#pragma unroll
        for (int i = 0; i < 8; i++) {
            a0[i] = bf2f((ushort)sv[i]);
            a1[i] = 0.f; a2[i] = 0.f; a3[i] = 0.f;
        }
    }
    for (int base = e0; base < e1; base += 8) {
        int m = min(8, e1 - base);
        int sg = (base + g < e1) ? edge_src[base + g] : 0;
        int j = 0;
        for (; j + 4 <= m; j += 4) {
            int s0 = __shfl(sg, j, 8);
            int s1 = __shfl(sg, j + 1, 8);
            int s2 = __shfl(sg, j + 2, 8);
            int s3 = __shfl(sg, j + 3, 8);
            short8 v0 = y8[(size_t)s0 * 8 + g];
            short8 v1 = y8[(size_t)s1 * 8 + g];
            short8 v2 = y8[(size_t)s2 * 8 + g];
            short8 v3 = y8[(size_t)s3 * 8 + g];
#pragma unroll
            for (int i = 0; i < 8; i++) {
                a0[i] += bf2f((ushort)v0[i]);
                a1[i] += bf2f((ushort)v1[i]);
                a2[i] += bf2f((ushort)v2[i]);
                a3[i] += bf2f((ushort)v3[i]);
            }
        }
        for (; j < m; ++j) {
            int s = __shfl(sg, j, 8);
            short8 v = y8[(size_t)s * 8 + g];
#pragma unroll
            for (int i = 0; i < 8; i++) a0[i] += bf2f((ushort)v[i]);
        }
    }
    float inv = 1.0f / (float)(e1 - e0 + 1);
    const float4* b4 = reinterpret_cast<const float4*>(b);
    float4 bv0 = b4[g * 2], bv1 = b4[g * 2 + 1];
    float4 o0, o1;
    o0.x = (a0[0] + a1[0] + a2[0] + a3[0]) * inv + bv0.x;
    o0.y = (a0[1] + a1[1] + a2[1] + a3[1]) * inv + bv0.y;
    o0.z = (a0[2] + a1[2] + a2[2] + a3[2]) * inv + bv0.z;
    o0.w = (a0[3] + a1[3] + a2[3] + a3[3]) * inv + bv0.w;
    o1.x = (a0[4] + a1[4] + a2[4] + a3[4]) * inv + bv1.x;
    o1.y = (a0[5] + a1[5] + a2[5] + a3[5]) * inv + bv1.y;
    o1.z = (a0[6] + a1[6] + a2[6] + a3[6]) * inv + bv1.z;
    o1.w = (a0[7] + a1[7] + a2[7] + a3[7]) * inv + bv1.w;
    float4* outp = reinterpret_cast<float4*>(out + (size_t)node * 64 + g * 8);
    outp[0] = o0;
    outp[1] = o1;
}

// ---------------------------------------------------------------------------
// Fused double GEMM: h = relu(A @ W1 + b1); y = h @ W2.  All bf16, fp32 MFMA
// accum.  W1 staged in LDS; W2 fragments read straight from global (L2-hot,
// only 16KB).  LDS = As + Ws1 = 52.2KB -> 3 blocks/CU.
__global__ __launch_bounds__(256) void gemm12_kernel(
    const ushort* __restrict__ A, const ushort* __restrict__ W1t,
    const float* __restrict__ b1, const ushort* __restrict__ W2t,
    ushort* __restrict__ y, int n_nodes) {
    __shared__ ushort As[64][136];
    __shared__ ushort Ws1[128][136];

    int t = threadIdx.x;
    int row0 = blockIdx.x * 64;
    for (int i = t; i < 64 * 16; i += 256) {       // stage A
        int r = i >> 4, c = i & 15;
        int gr = row0 + r;
        short8 v = {};
        if (gr < n_nodes)
            v = *reinterpret_cast<const short8*>(&A[(size_t)gr * NF + c * 8]);
        *reinterpret_cast<short8*>(&As[r][c * 8]) = v;
    }
    for (int i = t; i < 128 * 16; i += 256) {      // stage W1t
        int r = i >> 4, c = i & 15;
        *reinterpret_cast<short8*>(&Ws1[r][c * 8]) =
            *reinterpret_cast<const short8*>(&W1t[r * NF + c * 8]);
    }
    __syncthreads();

    int w = t >> 6;
    int l = t & 63;
    int m16 = l & 15;
    int g = l >> 4;
    int m0 = w * 16;

    // GEMM 1: acc1[nt] = A-tile @ W1 (8 col-tiles)
    f32x4 acc1[8];
#pragma unroll
    for (int nt = 0; nt < 8; nt++) acc1[nt] = {0.f, 0.f, 0.f, 0.f};
#pragma unroll
    for (int kk = 0; kk < 4; kk++) {
        int k0 = kk * 32 + g * 8;
        short8 a = *reinterpret_cast<const short8*>(&As[m0 + m16][k0]);
#pragma unroll
        for (int nt = 0; nt < 8; nt++) {
            short8 b = *reinterpret_cast<const short8*>(&Ws1[nt * 16 + m16][k0]);
            acc1[nt] = __builtin_amdgcn_mfma_f32_16x16x32_bf16(a, b, acc1[nt], 0, 0, 0);
        }
    }
    __syncthreads();   // all As reads done; reuse As for h

    // bias + relu + bf16, write h into As
#pragma unroll
    for (int nt = 0; nt < 8; nt++) {
        int col = nt * 16 + m16;
        float bv = b1[col];
#pragma unroll
        for (int i = 0; i < 4; i++) {
            int r = m0 + g * 4 + i;
            As[r][col] = f2bf(fmaxf(acc1[nt][i] + bv, 0.f));
        }
    }
    __syncthreads();

    // GEMM 2: y-tile = h @ W2 (4 col-tiles), W2 fragments from global
    f32x4 acc2[4];
#pragma unroll
    for (int nt = 0; nt < 4; nt++) acc2[nt] = {0.f, 0.f, 0.f, 0.f};
#pragma unroll
    for (int kk = 0; kk < 4; kk++) {
        int k0 = kk * 32 + g * 8;
        short8 a = *reinterpret_cast<const short8*>(&As[m0 + m16][k0]);
#pragma unroll
        for (int nt = 0; nt < 4; nt++) {
            short8 b = *reinterpret_cast<const short8*>(
                &W2t[(size_t)(nt * 16 + m16) * NF + k0]);
            acc2[nt] = __builtin_amdgcn_mfma_f32_16x16x32_bf16(a, b, acc2[nt], 0, 0, 0);
        }
    }

#pragma unroll
    for (int nt = 0; nt < 4; nt++) {
        int col = nt * 16 + m16;
#pragma unroll
        for (int i = 0; i < 4; i++) {
            int gr = row0 + m0 + g * 4 + i;
            if (gr < n_nodes)
                y[(size_t)gr * 64 + col] = f2bf(acc2[nt][i]);
        }
    }
}

// ---------------------------------------------------------------------------
extern "C" void kernel_launch(void* const* d_in, const int* in_sizes, int n_in,
                              void* d_out, int out_size, void* d_ws, size_t ws_size,
                              hipStream_t stream) {
    const float* x   = (const float*)d_in[0];
    const int*   src = (const int*)d_in[1];
    const int*   dst = (const int*)d_in[2];
    const float* W1  = (const float*)d_in[3];
    const float* b1  = (const float*)d_in[4];
    const float* W2  = (const float*)d_in[5];
    const float* b2  = (const float*)d_in[6];
    float* out = (float*)d_out;

    int n_nodes = in_sizes[0] / NF;   // 50000
    int n_edges = in_sizes[1];        // 600000
    int nb = (n_nodes + 255) / 256;   // 196
    int n8 = n_nodes * NF / 8;

    // ws: rowptr | cnt | cursor | edge_src | W1t | W2t | xb | hn | y
    int* rowptr   = (int*)d_ws;
    int* cnt      = rowptr + (n_nodes + 4);
    int* cursor   = cnt + n_nodes;
    int* edge_src = cursor + n_nodes;
    size_t iw = (size_t)(n_nodes + 4) + n_nodes + n_nodes + n_edges;
    iw = (iw + 63) & ~(size_t)63;  // 256B align
    ushort* W1t = (ushort*)((int*)d_ws + iw);
    ushort* W2t = W1t + 128 * NF;
    ushort* xb  = W2t + 64 * NF;
    ushort* hn  = xb + (size_t)n_nodes * NF;
    ushort* y   = hn + (size_t)n_nodes * NF;

    int eb = (n_edges + 255) / 256;

    prep_kernel<<<1024, 256, 0, stream>>>(x, W1, W2, cnt, xb, W1t, W2t, n_nodes, n8);
    hist_kernel<<<eb, 256, 0, stream>>>(dst, cnt, n_edges);
    scan_apply_kernel<<<nb, 256, 0, stream>>>(cnt, rowptr, cursor, n_nodes);
    fill_kernel<<<eb, 256, 0, stream>>>(src, dst, cursor, edge_src, n_edges);

    aggregate_kernel<<<(n_nodes + 15) / 16, 256, 0, stream>>>(xb, rowptr, edge_src, hn, n_nodes);
    gemm12_kernel<<<(n_nodes + 63) / 64, 256, 0, stream>>>(hn, W1t, b1, W2t, y, n_nodes);
    aggregate64_kernel<<<(n_nodes + 31) / 32, 256, 0, stream>>>(y, rowptr, edge_src, b2, out, n_nodes);
}

// Round 12
// 154.677 us; speedup vs baseline: 1.0075x; 1.0075x over previous
//
#include <hip/hip_runtime.h>

#define NF 128

typedef __attribute__((ext_vector_type(8))) short short8;
typedef __attribute__((ext_vector_type(4))) float f32x4;

__device__ inline ushort f2bf(float f) {
    uint u = __float_as_uint(f);
    return (ushort)((u + 0x7FFFu + ((u >> 16) & 1u)) >> 16);  // RNE
}
__device__ inline float bf2f(ushort u) {
    return __uint_as_float(((uint)u) << 16);
}

// ---------------------------------------------------------------------------
// Fused prep: zero cnt + convert W1/W2 (transposed) and x to bf16.
__global__ __launch_bounds__(256) void prep_kernel(
    const float* __restrict__ x, const float* __restrict__ W1,
    const float* __restrict__ W2, int* __restrict__ cnt,
    ushort* __restrict__ xb, ushort* __restrict__ W1t, ushort* __restrict__ W2t,
    int n_nodes, int n8) {
    int gid = blockIdx.x * 256 + threadIdx.x;
    int gstride = gridDim.x * 256;
    for (int i = gid; i < n_nodes; i += gstride) cnt[i] = 0;
    for (int i = gid; i < 128 * 128; i += gstride) {
        int k = i >> 7, n = i & 127;
        W1t[n * NF + k] = f2bf(W1[i]);
    }
    for (int i = gid; i < 128 * 64; i += gstride) {
        int k = i >> 6, n = i & 63;
        W2t[n * NF + k] = f2bf(W2[i]);
    }
    const float4* in4 = reinterpret_cast<const float4*>(x);
    for (int i = gid; i < n8; i += gstride) {
        float4 v0 = in4[i * 2], v1 = in4[i * 2 + 1];
        short8 o;
        o[0] = (short)f2bf(v0.x); o[1] = (short)f2bf(v0.y);
        o[2] = (short)f2bf(v0.z); o[3] = (short)f2bf(v0.w);
        o[4] = (short)f2bf(v1.x); o[5] = (short)f2bf(v1.y);
        o[6] = (short)f2bf(v1.z); o[7] = (short)f2bf(v1.w);
        *reinterpret_cast<short8*>(&xb[i * 8]) = o;
    }
}

// ---------------------------------------------------------------------------
// cnt[dst[e]] += 1
__global__ void hist_kernel(const int* __restrict__ dst, int* __restrict__ cnt,
                            int n_edges) {
    int i = blockIdx.x * blockDim.x + threadIdx.x;
    if (i < n_edges) atomicAdd(&cnt[dst[i]], 1);
}

// ---------------------------------------------------------------------------
// Fused reduce+scan: block b computes off0 = sum(cnt[0..b*256)) directly
// (cnt READ-ONLY; L2-resident), then block-local inclusive scan.
// rowptr[i+1] = off0+incl; cursor[i] = off0+excl; rowptr[0] = 0.
__global__ __launch_bounds__(256) void scan_apply_kernel(
    const int* __restrict__ cnt, int* __restrict__ rowptr,
    int* __restrict__ cursor, int n) {
    __shared__ int s[256];
    __shared__ int off0_sh;
    int t = threadIdx.x;
    int lim = (int)blockIdx.x * 256;
    int sum = 0;
    for (int i = t; i < lim; i += 256) sum += cnt[i];
    s[t] = sum;
    __syncthreads();
    for (int off = 128; off > 0; off >>= 1) {
        if (t < off) s[t] += s[t + off];
        __syncthreads();
    }
    if (t == 0) off0_sh = s[0];
    __syncthreads();
    int off0 = off0_sh;
    __syncthreads();
    int i = lim + t;
    int v = (i < n) ? cnt[i] : 0;
    s[t] = v;
    __syncthreads();
    for (int off = 1; off < 256; off <<= 1) {
        int a = (t >= off) ? s[t - off] : 0;
        __syncthreads();
        s[t] += a;
        __syncthreads();
    }
    if (i < n) {
        rowptr[i + 1] = off0 + s[t];
        cursor[i] = off0 + s[t] - v;
    }
    if (blockIdx.x == 0 && t == 0) rowptr[0] = 0;
}

// ---------------------------------------------------------------------------
// edge_src[cursor[dst[e]]++] = src[e]
__global__ void fill_kernel(const int* __restrict__ src,
                            const int* __restrict__ dst,
                            int* __restrict__ cursor,
                            int* __restrict__ edge_src, int n_edges) {
    int i = blockIdx.x * blockDim.x + threadIdx.x;
    if (i < n_edges) {
        int slot = atomicAdd(&cursor[dst[i]], 1);
        edge_src[slot] = src[i];
    }
}

// ---------------------------------------------------------------------------
// hn[i] = bf16( (sum_nbrs hb[j] + hb[i]) / (deg+1) ).  128-dim bf16 in/out.
// 32 lanes/node, ushort4 (8B) per lane; low VGPR (28) for full occupancy.
__global__ __launch_bounds__(256) void aggregate_kernel(
    const ushort* __restrict__ hb, const int* __restrict__ rowptr,
    const int* __restrict__ edge_src, ushort* __restrict__ hn, int n_nodes) {
    int t = threadIdx.x;
    int g = t & 31;
    int node = blockIdx.x * 8 + (t >> 5);
    if (node >= n_nodes) return;
    const ushort4* h4 = reinterpret_cast<const ushort4*>(hb);
    int e0 = rowptr[node], e1 = rowptr[node + 1];
    ushort4 sv = h4[(size_t)node * 32 + g];  // self term
    float a0x = bf2f(sv.x), a0y = bf2f(sv.y), a0z = bf2f(sv.z), a0w = bf2f(sv.w);
    float a1x = 0.f, a1y = 0.f, a1z = 0.f, a1w = 0.f;
    float a2x = 0.f, a2y = 0.f, a2z = 0.f, a2w = 0.f;
    float a3x = 0.f, a3y = 0.f, a3z = 0.f, a3w = 0.f;
    for (int base = e0; base < e1; base += 32) {
        int m = min(32, e1 - base);
        int sg = (base + g < e1) ? edge_src[base + g] : 0;
        int j = 0;
        for (; j + 4 <= m; j += 4) {
            int s0 = __shfl(sg, j, 32);
            int s1 = __shfl(sg, j + 1, 32);
            int s2 = __shfl(sg, j + 2, 32);
            int s3 = __shfl(sg, j + 3, 32);
            ushort4 v0 = h4[(size_t)s0 * 32 + g];
            ushort4 v1 = h4[(size_t)s1 * 32 + g];
            ushort4 v2 = h4[(size_t)s2 * 32 + g];
            ushort4 v3 = h4[(size_t)s3 * 32 + g];
            a0x += bf2f(v0.x); a0y += bf2f(v0.y); a0z += bf2f(v0.z); a0w += bf2f(v0.w);
            a1x += bf2f(v1.x); a1y += bf2f(v1.y); a1z += bf2f(v1.z); a1w += bf2f(v1.w);
            a2x += bf2f(v2.x); a2y += bf2f(v2.y); a2z += bf2f(v2.z); a2w += bf2f(v2.w);
            a3x += bf2f(v3.x); a3y += bf2f(v3.y); a3z += bf2f(v3.z); a3w += bf2f(v3.w);
        }
        for (; j < m; ++j) {
            int s = __shfl(sg, j, 32);
            ushort4 v = h4[(size_t)s * 32 + g];
            a0x += bf2f(v.x); a0y += bf2f(v.y); a0z += bf2f(v.z); a0w += bf2f(v.w);
        }
    }
    float inv = 1.0f / (float)(e1 - e0 + 1);
    ushort4 o;
    o.x = f2bf((a0x + a1x + a2x + a3x) * inv);
    o.y = f2bf((a0y + a1y + a2y + a3y) * inv);
    o.z = f2bf((a0z + a1z + a2z + a3z) * inv);
    o.w = f2bf((a0w + a1w + a2w + a3w) * inv);
    reinterpret_cast<ushort4*>(hn)[(size_t)node * 32 + g] = o;
}

// ---------------------------------------------------------------------------
// out[i] = (sum_nbrs y[j] + y[i]) / (deg+1) + b.   64-dim bf16 in, fp32 out.
// 16 lanes/node, ushort4 per lane.
__global__ __launch_bounds__(256) void aggregate64_kernel(
    const ushort* __restrict__ y, const int* __restrict__ rowptr,
    const int* __restrict__ edge_src, const float* __restrict__ b,
    float* __restrict__ out, int n_nodes) {
    int t = threadIdx.x;
    int g = t & 15;
    int node = blockIdx.x * 16 + (t >> 4);
    if (node >= n_nodes) return;
    const ushort4* y4 = reinterpret_cast<const ushort4*>(y);
    int e0 = rowptr[node], e1 = rowptr[node + 1];
    ushort4 sv = y4[(size_t)node * 16 + g];  // self term
    float a0x = bf2f(sv.x), a0y = bf2f(sv.y), a0z = bf2f(sv.z), a0w = bf2f(sv.w);
    float a1x = 0.f, a1y = 0.f, a1z = 0.f, a1w = 0.f;
    float a2x = 0.f, a2y = 0.f, a2z = 0.f, a2w = 0.f;
    float a3x = 0.f, a3y = 0.f, a3z = 0.f, a3w = 0.f;
    for (int base = e0; base < e1; base += 16) {
        int m = min(16, e1 - base);
        int sg = (base + g < e1) ? edge_src[base + g] : 0;
        int j = 0;
        for (; j + 4 <= m; j += 4) {
            int s0 = __shfl(sg, j, 16);
            int s1 = __shfl(sg, j + 1, 16);
            int s2 = __shfl(sg, j + 2, 16);
            int s3 = __shfl(sg, j + 3, 16);
            ushort4 v0 = y4[(size_t)s0 * 16 + g];
            ushort4 v1 = y4[(size_t)s1 * 16 + g];
            ushort4 v2 = y4[(size_t)s2 * 16 + g];
            ushort4 v3 = y4[(size_t)s3 * 16 + g];
            a0x += bf2f(v0.x); a0y += bf2f(v0.y); a0z += bf2f(v0.z); a0w += bf2f(v0.w);
            a1x += bf2f(v1.x); a1y += bf2f(v1.y); a1z += bf2f(v1.z); a1w += bf2f(v1.w);
            a2x += bf2f(v2.x); a2y += bf2f(v2.y); a2z += bf2f(v2.z); a2w += bf2f(v2.w);
            a3x += bf2f(v3.x); a3y += bf2f(v3.y); a3z += bf2f(v3.z); a3w += bf2f(v3.w);
        }
        for (; j < m; ++j) {
            int s = __shfl(sg, j, 16);
            ushort4 v = y4[(size_t)s * 16 + g];
            a0x += bf2f(v.x); a0y += bf2f(v.y); a0z += bf2f(v.z); a0w += bf2f(v.w);
        }
    }
    float inv = 1.0f / (float)(e1 - e0 + 1);
    float4 bv = reinterpret_cast<const float4*>(b)[g];
    float4 o;
    o.x = (a0x + a1x + a2x + a3x) * inv + bv.x;
    o.y = (a0y + a1y + a2y + a3y) * inv + bv.y;
    o.z = (a0z + a1z + a2z + a3z) * inv + bv.z;
    o.w = (a0w + a1w + a2w + a3w) * inv + bv.w;
    reinterpret_cast<float4*>(out)[(size_t)node * 16 + g] = o;
}

// ---------------------------------------------------------------------------
// Fused double GEMM: h = relu(A @ W1 + b1); y = h @ W2.  All bf16, fp32 MFMA
// accum.  W1,W2 staged in LDS (69.6KB -> 2 blocks/CU); h round-trips via As.
// Frag: m/n = lane&15, k = 8*(lane>>4)+i.  C/D: col=lane&15, row=4*(lane>>4)+i.
__global__ __launch_bounds__(256) void gemm12_kernel(
    const ushort* __restrict__ A, const ushort* __restrict__ W1t,
    const float* __restrict__ b1, const ushort* __restrict__ W2t,
    ushort* __restrict__ y, int n_nodes) {
    __shared__ ushort As[64][136];
    __shared__ ushort Ws1[128][136];
    __shared__ ushort Ws2[64][136];

    int t = threadIdx.x;
    int row0 = blockIdx.x * 64;
    for (int i = t; i < 64 * 16; i += 256) {       // stage A
        int r = i >> 4, c = i & 15;
        int gr = row0 + r;
        short8 v = {};
        if (gr < n_nodes)
            v = *reinterpret_cast<const short8*>(&A[(size_t)gr * NF + c * 8]);
        *reinterpret_cast<short8*>(&As[r][c * 8]) = v;
    }
    for (int i = t; i < 128 * 16; i += 256) {      // stage W1t
        int r = i >> 4, c = i & 15;
        *reinterpret_cast<short8*>(&Ws1[r][c * 8]) =
            *reinterpret_cast<const short8*>(&W1t[r * NF + c * 8]);
    }
    for (int i = t; i < 64 * 16; i += 256) {       // stage W2t
        int r = i >> 4, c = i & 15;
        *reinterpret_cast<short8*>(&Ws2[r][c * 8]) =
            *reinterpret_cast<const short8*>(&W2t[r * NF + c * 8]);
    }
    __syncthreads();

    int w = t >> 6;
    int l = t & 63;
    int m16 = l & 15;
    int g = l >> 4;
    int m0 = w * 16;

    // GEMM 1: acc1[nt] = A-tile @ W1 (8 col-tiles)
    f32x4 acc1[8];
#pragma unroll
    for (int nt = 0; nt < 8; nt++) acc1[nt] = {0.f, 0.f, 0.f, 0.f};
#pragma unroll
    for (int kk = 0; kk < 4; kk++) {
        int k0 = kk * 32 + g * 8;
        short8 a = *reinterpret_cast<const short8*>(&As[m0 + m16][k0]);
#pragma unroll
        for (int nt = 0; nt < 8; nt++) {
            short8 b = *reinterpret_cast<const short8*>(&Ws1[nt * 16 + m16][k0]);
            acc1[nt] = __builtin_amdgcn_mfma_f32_16x16x32_bf16(a, b, acc1[nt], 0, 0, 0);
        }
    }
    __syncthreads();   // all As reads done; reuse As for h

    // bias + relu + bf16, write h into As
#pragma unroll
    for (int nt = 0; nt < 8; nt++) {
        int col = nt * 16 + m16;
        float bv = b1[col];
#pragma unroll
        for (int i = 0; i < 4; i++) {
            int r = m0 + g * 4 + i;
            As[r][col] = f2bf(fmaxf(acc1[nt][i] + bv, 0.f));
        }
    }
    __syncthreads();

    // GEMM 2: y-tile = h @ W2 (4 col-tiles)
    f32x4 acc2[4];
#pragma unroll
    for (int nt = 0; nt < 4; nt++) acc2[nt] = {0.f, 0.f, 0.f, 0.f};
#pragma unroll
    for (int kk = 0; kk < 4; kk++) {
        int k0 = kk * 32 + g * 8;
        short8 a = *reinterpret_cast<const short8*>(&As[m0 + m16][k0]);
#pragma unroll
        for (int nt = 0; nt < 4; nt++) {
            short8 b = *reinterpret_cast<const short8*>(&Ws2[nt * 16 + m16][k0]);
            acc2[nt] = __builtin_amdgcn_mfma_f32_16x16x32_bf16(a, b, acc2[nt], 0, 0, 0);
        }
    }

#pragma unroll
    for (int nt = 0; nt < 4; nt++) {
        int col = nt * 16 + m16;
#pragma unroll
        for (int i = 0; i < 4; i++) {
            int gr = row0 + m0 + g * 4 + i;
            if (gr < n_nodes)
                y[(size_t)gr * 64 + col] = f2bf(acc2[nt][i]);
        }
    }
}

// ---------------------------------------------------------------------------
extern "C" void kernel_launch(void* const* d_in, const int* in_sizes, int n_in,
                              void* d_out, int out_size, void* d_ws, size_t ws_size,
                              hipStream_t stream) {
    const float* x   = (const float*)d_in[0];
    const int*   src = (const int*)d_in[1];
    const int*   dst = (const int*)d_in[2];
    const float* W1  = (const float*)d_in[3];
    const float* b1  = (const float*)d_in[4];
    const float* W2  = (const float*)d_in[5];
    const float* b2  = (const float*)d_in[6];
    float* out = (float*)d_out;

    int n_nodes = in_sizes[0] / NF;   // 50000
    int n_edges = in_sizes[1];        // 600000
    int nb = (n_nodes + 255) / 256;   // 196
    int n8 = n_nodes * NF / 8;

    // ws: rowptr | cnt | cursor | edge_src | W1t | W2t | xb | hn | y
    int* rowptr   = (int*)d_ws;
    int* cnt      = rowptr + (n_nodes + 4);
    int* cursor   = cnt + n_nodes;
    int* edge_src = cursor + n_nodes;
    size_t iw = (size_t)(n_nodes + 4) + n_nodes + n_nodes + n_edges;
    iw = (iw + 63) & ~(size_t)63;  // 256B align
    ushort* W1t = (ushort*)((int*)d_ws + iw);
    ushort* W2t = W1t + 128 * NF;
    ushort* xb  = W2t + 64 * NF;
    ushort* hn  = xb + (size_t)n_nodes * NF;
    ushort* y   = hn + (size_t)n_nodes * NF;

    int eb = (n_edges + 255) / 256;

    prep_kernel<<<1024, 256, 0, stream>>>(x, W1, W2, cnt, xb, W1t, W2t, n_nodes, n8);
    hist_kernel<<<eb, 256, 0, stream>>>(dst, cnt, n_edges);
    scan_apply_kernel<<<nb, 256, 0, stream>>>(cnt, rowptr, cursor, n_nodes);
    fill_kernel<<<eb, 256, 0, stream>>>(src, dst, cursor, edge_src, n_edges);

    aggregate_kernel<<<(n_nodes + 7) / 8, 256, 0, stream>>>(xb, rowptr, edge_src, hn, n_nodes);
    gemm12_kernel<<<(n_nodes + 63) / 64, 256, 0, stream>>>(hn, W1t, b1, W2t, y, n_nodes);
    aggregate64_kernel<<<(n_nodes + 15) / 16, 256, 0, stream>>>(y, rowptr, edge_src, b2, out, n_nodes);
}

// Round 13
// 131.728 us; speedup vs baseline: 1.1831x; 1.1742x over previous
//
#include <hip/hip_runtime.h>

#define NF 128

typedef __attribute__((ext_vector_type(8))) short short8;
typedef __attribute__((ext_vector_type(4))) float f32x4;

__device__ inline ushort f2bf(float f) {
    uint u = __float_as_uint(f);
    return (ushort)((u + 0x7FFFu + ((u >> 16) & 1u)) >> 16);  // RNE
}
__device__ inline float bf2f(ushort u) {
    return __uint_as_float(((uint)u) << 16);
}

// ---------------------------------------------------------------------------
// Fused prep: zero cnt + convert W1/W2 (transposed) and x to bf16.
__global__ __launch_bounds__(256) void prep_kernel(
    const float* __restrict__ x, const float* __restrict__ W1,
    const float* __restrict__ W2, int* __restrict__ cnt,
    ushort* __restrict__ xb, ushort* __restrict__ W1t, ushort* __restrict__ W2t,
    int n_nodes, int n8) {
    int gid = blockIdx.x * 256 + threadIdx.x;
    int gstride = gridDim.x * 256;
    for (int i = gid; i < n_nodes; i += gstride) cnt[i] = 0;
    for (int i = gid; i < 128 * 128; i += gstride) {
        int k = i >> 7, n = i & 127;
        W1t[n * NF + k] = f2bf(W1[i]);
    }
    for (int i = gid; i < 128 * 64; i += gstride) {
        int k = i >> 6, n = i & 63;
        W2t[n * NF + k] = f2bf(W2[i]);
    }
    const float4* in4 = reinterpret_cast<const float4*>(x);
    for (int i = gid; i < n8; i += gstride) {
        float4 v0 = in4[i * 2], v1 = in4[i * 2 + 1];
        short8 o;
        o[0] = (short)f2bf(v0.x); o[1] = (short)f2bf(v0.y);
        o[2] = (short)f2bf(v0.z); o[3] = (short)f2bf(v0.w);
        o[4] = (short)f2bf(v1.x); o[5] = (short)f2bf(v1.y);
        o[6] = (short)f2bf(v1.z); o[7] = (short)f2bf(v1.w);
        *reinterpret_cast<short8*>(&xb[i * 8]) = o;
    }
}

// ---------------------------------------------------------------------------
// cnt[dst[e]] += 1, 4 edges/thread (int4 loads)
__global__ void hist_kernel(const int* __restrict__ dst, int* __restrict__ cnt,
                            int n_edges) {
    int i4 = blockIdx.x * blockDim.x + threadIdx.x;
    int base = i4 * 4;
    if (base + 3 < n_edges) {
        int4 d = *reinterpret_cast<const int4*>(&dst[base]);
        atomicAdd(&cnt[d.x], 1);
        atomicAdd(&cnt[d.y], 1);
        atomicAdd(&cnt[d.z], 1);
        atomicAdd(&cnt[d.w], 1);
    } else {
        for (int k = base; k < n_edges; ++k) atomicAdd(&cnt[dst[k]], 1);
    }
}

// ---------------------------------------------------------------------------
// partials[b] = sum(cnt[b*256 : (b+1)*256])
__global__ __launch_bounds__(256) void reduce_kernel(const int* __restrict__ cnt,
                                                     int* __restrict__ partials,
                                                     int n) {
    __shared__ int s[256];
    int t = threadIdx.x;
    int i = blockIdx.x * 256 + t;
    s[t] = (i < n) ? cnt[i] : 0;
    __syncthreads();
    for (int off = 128; off > 0; off >>= 1) {
        if (t < off) s[t] += s[t + off];
        __syncthreads();
    }
    if (t == 0) partials[blockIdx.x] = s[0];
}

// ---------------------------------------------------------------------------
// off0 = sum(partials[0..bid)) via one load/thread + tree reduce (nb<=256),
// then block-local scan.  rowptr[i+1]=off0+incl; cursor[i]=off0+excl.
__global__ __launch_bounds__(256) void scan_apply_kernel(
    const int* __restrict__ cnt, int* __restrict__ rowptr,
    int* __restrict__ cursor, const int* __restrict__ partials, int n) {
    __shared__ int s[256];
    __shared__ int off0_sh;
    int t = threadIdx.x;
    s[t] = (t < (int)blockIdx.x) ? partials[t] : 0;
    __syncthreads();
    for (int off = 128; off > 0; off >>= 1) {
        if (t < off) s[t] += s[t + off];
        __syncthreads();
    }
    if (t == 0) off0_sh = s[0];
    __syncthreads();
    int off0 = off0_sh;
    __syncthreads();
    int i = blockIdx.x * 256 + t;
    int v = (i < n) ? cnt[i] : 0;
    s[t] = v;
    __syncthreads();
    for (int off = 1; off < 256; off <<= 1) {
        int a = (t >= off) ? s[t - off] : 0;
        __syncthreads();
        s[t] += a;
        __syncthreads();
    }
    if (i < n) {
        rowptr[i + 1] = off0 + s[t];
        cursor[i] = off0 + s[t] - v;
    }
    if (blockIdx.x == 0 && t == 0) rowptr[0] = 0;
}

// ---------------------------------------------------------------------------
// edge_src[cursor[dst[e]]++] = src[e], 4 edges/thread
__global__ void fill_kernel(const int* __restrict__ src,
                            const int* __restrict__ dst,
                            int* __restrict__ cursor,
                            int* __restrict__ edge_src, int n_edges) {
    int i4 = blockIdx.x * blockDim.x + threadIdx.x;
    int base = i4 * 4;
    if (base + 3 < n_edges) {
        int4 d = *reinterpret_cast<const int4*>(&dst[base]);
        int4 sc = *reinterpret_cast<const int4*>(&src[base]);
        edge_src[atomicAdd(&cursor[d.x], 1)] = sc.x;
        edge_src[atomicAdd(&cursor[d.y], 1)] = sc.y;
        edge_src[atomicAdd(&cursor[d.z], 1)] = sc.z;
        edge_src[atomicAdd(&cursor[d.w], 1)] = sc.w;
    } else {
        for (int k = base; k < n_edges; ++k)
            edge_src[atomicAdd(&cursor[dst[k]], 1)] = src[k];
    }
}

// ---------------------------------------------------------------------------
// hn[i] = bf16( (sum_nbrs hb[j] + hb[i]) / (deg+1) ).  128-dim bf16 in/out.
// 32 lanes/node, ushort4 (8B) per lane; low VGPR for full occupancy.
__global__ __launch_bounds__(256) void aggregate_kernel(
    const ushort* __restrict__ hb, const int* __restrict__ rowptr,
    const int* __restrict__ edge_src, ushort* __restrict__ hn, int n_nodes) {
    int t = threadIdx.x;
    int g = t & 31;
    int node = blockIdx.x * 8 + (t >> 5);
    if (node >= n_nodes) return;
    const ushort4* h4 = reinterpret_cast<const ushort4*>(hb);
    int e0 = rowptr[node], e1 = rowptr[node + 1];
    ushort4 sv = h4[(size_t)node * 32 + g];  // self term
    float a0x = bf2f(sv.x), a0y = bf2f(sv.y), a0z = bf2f(sv.z), a0w = bf2f(sv.w);
    float a1x = 0.f, a1y = 0.f, a1z = 0.f, a1w = 0.f;
    float a2x = 0.f, a2y = 0.f, a2z = 0.f, a2w = 0.f;
    float a3x = 0.f, a3y = 0.f, a3z = 0.f, a3w = 0.f;
    for (int base = e0; base < e1; base += 32) {
        int m = min(32, e1 - base);
        int sg = (base + g < e1) ? edge_src[base + g] : 0;
        int j = 0;
        for (; j + 4 <= m; j += 4) {
            int s0 = __shfl(sg, j, 32);
            int s1 = __shfl(sg, j + 1, 32);
            int s2 = __shfl(sg, j + 2, 32);
            int s3 = __shfl(sg, j + 3, 32);
            ushort4 v0 = h4[(size_t)s0 * 32 + g];
            ushort4 v1 = h4[(size_t)s1 * 32 + g];
            ushort4 v2 = h4[(size_t)s2 * 32 + g];
            ushort4 v3 = h4[(size_t)s3 * 32 + g];
            a0x += bf2f(v0.x); a0y += bf2f(v0.y); a0z += bf2f(v0.z); a0w += bf2f(v0.w);
            a1x += bf2f(v1.x); a1y += bf2f(v1.y); a1z += bf2f(v1.z); a1w += bf2f(v1.w);
            a2x += bf2f(v2.x); a2y += bf2f(v2.y); a2z += bf2f(v2.z); a2w += bf2f(v2.w);
            a3x += bf2f(v3.x); a3y += bf2f(v3.y); a3z += bf2f(v3.z); a3w += bf2f(v3.w);
        }
        for (; j < m; ++j) {
            int s = __shfl(sg, j, 32);
            ushort4 v = h4[(size_t)s * 32 + g];
            a0x += bf2f(v.x); a0y += bf2f(v.y); a0z += bf2f(v.z); a0w += bf2f(v.w);
        }
    }
    float inv = 1.0f / (float)(e1 - e0 + 1);
    ushort4 o;
    o.x = f2bf((a0x + a1x + a2x + a3x) * inv);
    o.y = f2bf((a0y + a1y + a2y + a3y) * inv);
    o.z = f2bf((a0z + a1z + a2z + a3z) * inv);
    o.w = f2bf((a0w + a1w + a2w + a3w) * inv);
    reinterpret_cast<ushort4*>(hn)[(size_t)node * 32 + g] = o;
}

// ---------------------------------------------------------------------------
// out[i] = (sum_nbrs y[j] + y[i]) / (deg+1) + b.   64-dim bf16 in, fp32 out.
// 16 lanes/node, ushort4 per lane.
__global__ __launch_bounds__(256) void aggregate64_kernel(
    const ushort* __restrict__ y, const int* __restrict__ rowptr,
    const int* __restrict__ edge_src, const float* __restrict__ b,
    float* __restrict__ out, int n_nodes) {
    int t = threadIdx.x;
    int g = t & 15;
    int node = blockIdx.x * 16 + (t >> 4);
    if (node >= n_nodes) return;
    const ushort4* y4 = reinterpret_cast<const ushort4*>(y);
    int e0 = rowptr[node], e1 = rowptr[node + 1];
    ushort4 sv = y4[(size_t)node * 16 + g];  // self term
    float a0x = bf2f(sv.x), a0y = bf2f(sv.y), a0z = bf2f(sv.z), a0w = bf2f(sv.w);
    float a1x = 0.f, a1y = 0.f, a1z = 0.f, a1w = 0.f;
    float a2x = 0.f, a2y = 0.f, a2z = 0.f, a2w = 0.f;
    float a3x = 0.f, a3y = 0.f, a3z = 0.f, a3w = 0.f;
    for (int base = e0; base < e1; base += 16) {
        int m = min(16, e1 - base);
        int sg = (base + g < e1) ? edge_src[base + g] : 0;
        int j = 0;
        for (; j + 4 <= m; j += 4) {
            int s0 = __shfl(sg, j, 16);
            int s1 = __shfl(sg, j + 1, 16);
            int s2 = __shfl(sg, j + 2, 16);
            int s3 = __shfl(sg, j + 3, 16);
            ushort4 v0 = y4[(size_t)s0 * 16 + g];
            ushort4 v1 = y4[(size_t)s1 * 16 + g];
            ushort4 v2 = y4[(size_t)s2 * 16 + g];
            ushort4 v3 = y4[(size_t)s3 * 16 + g];
            a0x += bf2f(v0.x); a0y += bf2f(v0.y); a0z += bf2f(v0.z); a0w += bf2f(v0.w);
            a1x += bf2f(v1.x); a1y += bf2f(v1.y); a1z += bf2f(v1.z); a1w += bf2f(v1.w);
            a2x += bf2f(v2.x); a2y += bf2f(v2.y); a2z += bf2f(v2.z); a2w += bf2f(v2.w);
            a3x += bf2f(v3.x); a3y += bf2f(v3.y); a3z += bf2f(v3.z); a3w += bf2f(v3.w);
        }
        for (; j < m; ++j) {
            int s = __shfl(sg, j, 16);
            ushort4 v = y4[(size_t)s * 16 + g];
            a0x += bf2f(v.x); a0y += bf2f(v.y); a0z += bf2f(v.z); a0w += bf2f(v.w);
        }
    }
    float inv = 1.0f / (float)(e1 - e0 + 1);
    float4 bv = reinterpret_cast<const float4*>(b)[g];
    float4 o;
    o.x = (a0x + a1x + a2x + a3x) * inv + bv.x;
    o.y = (a0y + a1y + a2y + a3y) * inv + bv.y;
    o.z = (a0z + a1z + a2z + a3z) * inv + bv.z;
    o.w = (a0w + a1w + a2w + a3w) * inv + bv.w;
    reinterpret_cast<float4*>(out)[(size_t)node * 16 + g] = o;
}

// ---------------------------------------------------------------------------
// Fused double GEMM: h = relu(A @ W1 + b1); y = h @ W2.  All bf16, fp32 MFMA
// accum.  W1,W2 staged in LDS (69.6KB -> 2 blocks/CU); h round-trips via As.
__global__ __launch_bounds__(256) void gemm12_kernel(
    const ushort* __restrict__ A, const ushort* __restrict__ W1t,
    const float* __restrict__ b1, const ushort* __restrict__ W2t,
    ushort* __restrict__ y, int n_nodes) {
    __shared__ ushort As[64][136];
    __shared__ ushort Ws1[128][136];
    __shared__ ushort Ws2[64][136];

    int t = threadIdx.x;
    int row0 = blockIdx.x * 64;
    for (int i = t; i < 64 * 16; i += 256) {       // stage A
        int r = i >> 4, c = i & 15;
        int gr = row0 + r;
        short8 v = {};
        if (gr < n_nodes)
            v = *reinterpret_cast<const short8*>(&A[(size_t)gr * NF + c * 8]);
        *reinterpret_cast<short8*>(&As[r][c * 8]) = v;
    }
    for (int i = t; i < 128 * 16; i += 256) {      // stage W1t
        int r = i >> 4, c = i & 15;
        *reinterpret_cast<short8*>(&Ws1[r][c * 8]) =
            *reinterpret_cast<const short8*>(&W1t[r * NF + c * 8]);
    }
    for (int i = t; i < 64 * 16; i += 256) {       // stage W2t
        int r = i >> 4, c = i & 15;
        *reinterpret_cast<short8*>(&Ws2[r][c * 8]) =
            *reinterpret_cast<const short8*>(&W2t[r * NF + c * 8]);
    }
    __syncthreads();

    int w = t >> 6;
    int l = t & 63;
    int m16 = l & 15;
    int g = l >> 4;
    int m0 = w * 16;

    // GEMM 1: acc1[nt] = A-tile @ W1 (8 col-tiles)
    f32x4 acc1[8];
#pragma unroll
    for (int nt = 0; nt < 8; nt++) acc1[nt] = {0.f, 0.f, 0.f, 0.f};
#pragma unroll
    for (int kk = 0; kk < 4; kk++) {
        int k0 = kk * 32 + g * 8;
        short8 a = *reinterpret_cast<const short8*>(&As[m0 + m16][k0]);
#pragma unroll
        for (int nt = 0; nt < 8; nt++) {
            short8 b = *reinterpret_cast<const short8*>(&Ws1[nt * 16 + m16][k0]);
            acc1[nt] = __builtin_amdgcn_mfma_f32_16x16x32_bf16(a, b, acc1[nt], 0, 0, 0);
        }
    }
    __syncthreads();   // all As reads done; reuse As for h

    // bias + relu + bf16, write h into As
#pragma unroll
    for (int nt = 0; nt < 8; nt++) {
        int col = nt * 16 + m16;
        float bv = b1[col];
#pragma unroll
        for (int i = 0; i < 4; i++) {
            int r = m0 + g * 4 + i;
            As[r][col] = f2bf(fmaxf(acc1[nt][i] + bv, 0.f));
        }
    }
    __syncthreads();

    // GEMM 2: y-tile = h @ W2 (4 col-tiles)
    f32x4 acc2[4];
#pragma unroll
    for (int nt = 0; nt < 4; nt++) acc2[nt] = {0.f, 0.f, 0.f, 0.f};
#pragma unroll
    for (int kk = 0; kk < 4; kk++) {
        int k0 = kk * 32 + g * 8;
        short8 a = *reinterpret_cast<const short8*>(&As[m0 + m16][k0]);
#pragma unroll
        for (int nt = 0; nt < 4; nt++) {
            short8 b = *reinterpret_cast<const short8*>(&Ws2[nt * 16 + m16][k0]);
            acc2[nt] = __builtin_amdgcn_mfma_f32_16x16x32_bf16(a, b, acc2[nt], 0, 0, 0);
        }
    }

#pragma unroll
    for (int nt = 0; nt < 4; nt++) {
        int col = nt * 16 + m16;
#pragma unroll
        for (int i = 0; i < 4; i++) {
            int gr = row0 + m0 + g * 4 + i;
            if (gr < n_nodes)
                y[(size_t)gr * 64 + col] = f2bf(acc2[nt][i]);
        }
    }
}

// ---------------------------------------------------------------------------
extern "C" void kernel_launch(void* const* d_in, const int* in_sizes, int n_in,
                              void* d_out, int out_size, void* d_ws, size_t ws_size,
                              hipStream_t stream) {
    const float* x   = (const float*)d_in[0];
    const int*   src = (const int*)d_in[1];
    const int*   dst = (const int*)d_in[2];
    const float* W1  = (const float*)d_in[3];
    const float* b1  = (const float*)d_in[4];
    const float* W2  = (const float*)d_in[5];
    const float* b2  = (const float*)d_in[6];
    float* out = (float*)d_out;

    int n_nodes = in_sizes[0] / NF;   // 50000
    int n_edges = in_sizes[1];        // 600000
    int nb = (n_nodes + 255) / 256;   // 196 (<=256 required)
    int n8 = n_nodes * NF / 8;

    // ws: rowptr | cnt | cursor | edge_src | partials[256] | W1t | W2t | xb | hn | y
    int* rowptr   = (int*)d_ws;
    int* cnt      = rowptr + (n_nodes + 4);
    int* cursor   = cnt + n_nodes;
    int* edge_src = cursor + n_nodes;
    int* partials = edge_src + n_edges;
    size_t iw = (size_t)(n_nodes + 4) + n_nodes + n_nodes + n_edges + 256;
    iw = (iw + 63) & ~(size_t)63;  // 256B align
    ushort* W1t = (ushort*)((int*)d_ws + iw);
    ushort* W2t = W1t + 128 * NF;
    ushort* xb  = W2t + 64 * NF;
    ushort* hn  = xb + (size_t)n_nodes * NF;
    ushort* y   = hn + (size_t)n_nodes * NF;

    int eb4 = (n_edges / 4 + 255) / 256;

    prep_kernel<<<1024, 256, 0, stream>>>(x, W1, W2, cnt, xb, W1t, W2t, n_nodes, n8);
    hist_kernel<<<eb4, 256, 0, stream>>>(dst, cnt, n_edges);
    reduce_kernel<<<nb, 256, 0, stream>>>(cnt, partials, n_nodes);
    scan_apply_kernel<<<nb, 256, 0, stream>>>(cnt, rowptr, cursor, partials, n_nodes);
    fill_kernel<<<eb4, 256, 0, stream>>>(src, dst, cursor, edge_src, n_edges);

    aggregate_kernel<<<(n_nodes + 7) / 8, 256, 0, stream>>>(xb, rowptr, edge_src, hn, n_nodes);
    gemm12_kernel<<<(n_nodes + 63) / 64, 256, 0, stream>>>(hn, W1t, b1, W2t, y, n_nodes);
    aggregate64_kernel<<<(n_nodes + 15) / 16, 256, 0, stream>>>(y, rowptr, edge_src, b2, out, n_nodes);
}